// Round 9
// baseline (74.727 us; speedup 1.0000x reference)
//
#include <hip/hip_runtime.h>
#include <hip/hip_bf16.h>

// CrossAttentionOutLayer: out[b,i,j] = (1/H) * sum_c Q'[b,i,c] * K[b,j,c]
//   Q' = SCALE*(rna@Wq.T + bq) + rel_bias   (c = h*DK+d == flat rel_bias idx)
//   K  = prot@Wk.T + bk
// B=8 N=1024 M=1024 DIM2=1280 KIN=1344 H=8 DK=64 HDK=512 SCALE=0.125
//
// R9: TLP, not deeper pipelining. R6/R8 showed all pipes <20% busy with
// 2 waves/SIMD — barrier-locked serial segments exposed (m114: wave-level
// overlap is what hides them). Same 128x128 tile, same swizzle, same
// depth-2 asm pipeline, but 8 waves/block (512 thr, 2x4 waves of 64x32)
// -> 2 blocks/CU x 8 = 16 waves/CU = 4/SIMD. Per-wave quantities halve
// (4-load sets, steady vmcnt(4)); VGPR ~120 fits the 128 cap of (512,4).

typedef __bf16 bf16x8 __attribute__((ext_vector_type(8)));
typedef __bf16 bf16x4 __attribute__((ext_vector_type(4)));
typedef float f32x4 __attribute__((ext_vector_type(4)));

__device__ inline bf16x4 cvt4(const f32x4 a) {
    bf16x4 r;
    r[0] = (__bf16)a[0]; r[1] = (__bf16)a[1];
    r[2] = (__bf16)a[2]; r[3] = (__bf16)a[3];
    return r;
}

// unsinkable 16B global load; dst EARLY-CLOBBER (never aliases addr regs).
// NO implicit wait — caller must s_waitcnt vmcnt before reading dst.
__device__ inline void gload4(f32x4& dst, const float* p) {
    asm volatile("global_load_dwordx4 %0, %1, off"
                 : "=&v"(dst) : "v"(p) : "memory");
}

// ---------------------------------------------------------------------------
// Fused Q+K projection. Tile 128x128, BK=64, 8 waves (2x4) of 64x32 each.
// bf16 double-buffered LDS (64KB -> 2 blocks/CU). grid 512, XCD swizzle.
// ---------------------------------------------------------------------------
__global__ __launch_bounds__(512, 4)
void proj_all(const float* __restrict__ rna,  const float* __restrict__ prot,
              const float* __restrict__ Wq,   const float* __restrict__ bq,
              const float* __restrict__ Wk,   const float* __restrict__ bk,
              const float* __restrict__ rb,
              __bf16* __restrict__ qout, __bf16* __restrict__ kout)
{
    __shared__ __bf16 AS[2][128 * 64];   // 2 x 16 KB
    __shared__ __bf16 WS[2][128 * 64];   // 2 x 16 KB

    const int bid = blockIdx.x;
    const int wg  = (bid & 7) * 64 + (bid >> 3);   // bijective XCD swizzle (512%8==0)
    const bool isQ = wg < 256;
    const int lwg  = isQ ? wg : wg - 256;
    const int brow = (lwg >> 2) * 128;
    const int bcol = (lwg & 3) * 128;

    const float* A    = isQ ? rna : prot;
    const float* W    = isQ ? Wq  : Wk;
    const float* bias = isQ ? bq  : bk;
    __bf16*      out  = isQ ? qout : kout;
    const int    K    = isQ ? 1280 : 1344;
    const int    nt   = K >> 6;          // 20 (Q) or 21 (K) steps

    const int tid  = threadIdx.x;
    const int lane = tid & 63;
    const int wid  = tid >> 6;           // 0..7
    const int wr   = wid >> 2;           // 0..1 -> 64-row half
    const int wc   = wid & 3;            // 0..3 -> 32-col strip
    const int fr   = lane & 15;
    const int q4   = lane >> 4;

    // staging: wave stages rows [wid*16, +16) of A and of W; 4 insts of 4 rows.
    // inst i: row rloc + 4i, f32 col fr*4 (quarter-wave = 256B coalesced).
    const int rloc = wid * 16 + q4;
    const float* aGlob = A + (size_t)(brow + rloc) * K + fr * 4;
    const float* wGlob = W + (size_t)(bcol + rloc) * K + fr * 4;
    // LDS write addr: mask3(row)=((row&3)<<1)|((row>>2)&1); row&3=q4,
    // (row>>2)&1 = i&1 (wid*16, 4i)  -> base XORs (q4<<1), inst i XORs bit4.
    const int lb = rloc * 128 + (((fr >> 1) ^ (q4 << 1)) << 4) + (lane & 1) * 8;
    // fragment-read swizzle (frag row&7 = fr&7)
    const int rmask = ((fr & 3) << 1) | ((fr >> 2) & 1);

    f32x4 acc[4][2] = {};
    f32x4 a0[4], a1[4], wv[4];           // A: two named sets; W: one (L2-hot)

#define ISSUE_A(k0, ra) do {                                              \
    _Pragma("unroll")                                                     \
    for (int i_ = 0; i_ < 4; ++i_)                                        \
        gload4(ra[i_], aGlob + (size_t)(i_ * 4) * K + (k0));              \
    } while (0)

#define ISSUE_W(k0) do {                                                  \
    _Pragma("unroll")                                                     \
    for (int i_ = 0; i_ < 4; ++i_)                                        \
        gload4(wv[i_], wGlob + (size_t)(i_ * 4) * K + (k0));              \
    } while (0)

#define STAGE(p, ra) do {                                                 \
    char* as_ = (char*)AS[p]; char* ws_ = (char*)WS[p];                   \
    _Pragma("unroll")                                                     \
    for (int i_ = 0; i_ < 4; ++i_) {                                      \
        *(bf16x4*)(as_ + ((lb ^ ((i_ & 1) << 4)) + i_ * 512)) = cvt4(ra[i_]); \
        *(bf16x4*)(ws_ + ((lb ^ ((i_ & 1) << 4)) + i_ * 512)) = cvt4(wv[i_]); \
    } } while (0)

#define COMPUTE(p) do {                                                   \
    const char* as_ = (const char*)AS[p];                                 \
    const char* ws_ = (const char*)WS[p];                                 \
    _Pragma("unroll")                                                     \
    for (int kk_ = 0; kk_ < 2; ++kk_) {                                   \
        bf16x8 af[4], bw[2];                                              \
        _Pragma("unroll")                                                 \
        for (int m_ = 0; m_ < 4; ++m_)                                    \
            af[m_] = *(const bf16x8*)(as_ + (wr * 64 + m_ * 16 + fr) * 128 \
                                          + (((kk_ * 4 + q4) ^ rmask) << 4)); \
        _Pragma("unroll")                                                 \
        for (int n_ = 0; n_ < 2; ++n_)                                    \
            bw[n_] = *(const bf16x8*)(ws_ + (wc * 32 + n_ * 16 + fr) * 128 \
                                          + (((kk_ * 4 + q4) ^ rmask) << 4)); \
        _Pragma("unroll")                                                 \
        for (int m_ = 0; m_ < 4; ++m_)                                    \
            _Pragma("unroll")                                             \
            for (int n_ = 0; n_ < 2; ++n_)                                \
                acc[m_][n_] = __builtin_amdgcn_mfma_f32_16x16x32_bf16(    \
                    af[m_], bw[n_], acc[m_][n_], 0, 0, 0);                \
    } } while (0)

// STEP(t): per-wave FIFO at entry = [A(t):4, W(t):4, A(t+1):4].
// vmcnt(4) -> A(t)+W(t) landed, A(t+1) stays in flight (T4: no drain).
// Then stage t, issue W(t+1) then A(t+2), raw s_barrier, compute.
#define STEP(t, p, ra) do {                                               \
    if ((t) + 1 < nt) asm volatile("s_waitcnt vmcnt(4)" ::: "memory");    \
    else              asm volatile("s_waitcnt vmcnt(0)" ::: "memory");    \
    __builtin_amdgcn_sched_barrier(0);   /* rule #18: no cvt hoist */     \
    STAGE(p, ra);                                                         \
    __builtin_amdgcn_sched_barrier(0);                                    \
    if ((t) + 1 < nt) ISSUE_W(((t) + 1) * 64);                            \
    if ((t) + 2 < nt) ISSUE_A(((t) + 2) * 64, ra);                        \
    __builtin_amdgcn_sched_barrier(0);                                    \
    asm volatile("s_waitcnt lgkmcnt(0)" ::: "memory");  /* ds visible */  \
    __builtin_amdgcn_s_barrier();        /* raw: does NOT drain vmcnt */  \
    __builtin_amdgcn_sched_barrier(0);                                    \
    COMPUTE(p);                                                           \
} while (0)

    // prologue: FIFO = [A(0), W(0), A(1)]
    ISSUE_A(0, a0);
    ISSUE_W(0);
    ISSUE_A(64, a1);

    int t = 0;
    for (; t + 1 < nt; t += 2) {         // pair-unroll keeps set/parity static
        STEP(t,     0, a0);
        STEP(t + 1, 1, a1);
    }
    if (t < nt) STEP(t, 0, a0);          // odd-nt tail (K-proj: nt=21)

#undef ISSUE_A
#undef ISSUE_W
#undef STAGE
#undef COMPUTE
#undef STEP

    // C/D layout: col = lane&15, row = (lane>>4)*4 + j  [m89-verified]
    const int r0 = (lane >> 4) * 4;
    #pragma unroll
    for (int n = 0; n < 2; ++n) {
        const int c = bcol + wc * 32 + n * 16 + fr;
        const float bv = bias[c];
        const float rv = isQ ? rb[c] : 0.0f;
        #pragma unroll
        for (int m = 0; m < 4; ++m) {
            const int row = brow + wr * 64 + m * 16 + r0;
            #pragma unroll
            for (int j = 0; j < 4; ++j) {
                float v = acc[m][n][j] + bv;
                if (isQ) v = 0.125f * v + rv;
                out[(size_t)(row + j) * 512 + c] = (__bf16)v;
            }
        }
    }
}

// ---------------------------------------------------------------------------
// Batched GEMM: out[b,i,j] = 0.125 * sum_c Q[b,i,c]*K[b,j,c]
// 128x128 tile, BK=64, gload_lds staging, swizzled bf16 LDS. (unchanged;
// ~9.6 us ~= its HBM floor: 33.5 MB write + 16 MB read)
// ---------------------------------------------------------------------------
__global__ __launch_bounds__(256, 2)
void attn_kernel(const __bf16* __restrict__ Q,
                 const __bf16* __restrict__ Kb,
                 float* __restrict__ out)
{
    __shared__ __bf16 As[128 * 64];   // 16 KB, linear dest (swizzled content)
    __shared__ __bf16 Bs[128 * 64];

    const int tid  = threadIdx.x;
    const int lane = tid & 63;
    const int wid  = tid >> 6;
    const int wr   = wid >> 1;
    const int wc   = wid & 1;
    const int b    = blockIdx.z;
    const int brow = blockIdx.y * 128;
    const int bcol = blockIdx.x * 128;

    const __bf16* Qb = Q  + (size_t)b * 1024 * 512;
    const __bf16* Kp = Kb + (size_t)b * 1024 * 512;

    const int fr = lane & 15;
    const int q4 = lane >> 4;

    f32x4 acc[4][4] = {};

    const int lr3 = lane >> 3;
    const int m3  = ((lr3 & 3) << 1) | ((lr3 >> 2) & 1);
    const int scol = ((lane & 7) ^ m3) * 8;            // swizzled global bf16 col
    const int rmask = ((fr & 3) << 1) | ((fr >> 2) & 1);

    for (int k0 = 0; k0 < 512; k0 += 64) {
        __syncthreads();
        #pragma unroll
        for (int i = 0; i < 4; ++i) {
            const int rbase = wid * 32 + i * 8;
            const __bf16* sa = Qb + (size_t)(brow + rbase + lr3) * 512 + k0 + scol;
            const __bf16* sb = Kp + (size_t)(bcol + rbase + lr3) * 512 + k0 + scol;
            __builtin_amdgcn_global_load_lds(
                (const __attribute__((address_space(1))) void*)sa,
                (__attribute__((address_space(3))) void*)&As[rbase * 64], 16, 0, 0);
            __builtin_amdgcn_global_load_lds(
                (const __attribute__((address_space(1))) void*)sb,
                (__attribute__((address_space(3))) void*)&Bs[rbase * 64], 16, 0, 0);
        }
        __syncthreads();

        #pragma unroll
        for (int kk = 0; kk < 2; ++kk) {
            const int ci = kk * 4 + q4;
            bf16x8 af[4], bf_[4];
            #pragma unroll
            for (int m = 0; m < 4; ++m)
                af[m] = *(const bf16x8*)(&As[(wr * 64 + m * 16 + fr) * 64 + ((ci ^ rmask) << 3)]);
            #pragma unroll
            for (int n = 0; n < 4; ++n)
                bf_[n] = *(const bf16x8*)(&Bs[(wc * 64 + n * 16 + fr) * 64 + ((ci ^ rmask) << 3)]);
            #pragma unroll
            for (int m = 0; m < 4; ++m)
                #pragma unroll
                for (int n = 0; n < 4; ++n)
                    acc[m][n] = __builtin_amdgcn_mfma_f32_16x16x32_bf16(af[m], bf_[n], acc[m][n], 0, 0, 0);
        }
    }

    float* op = out + (size_t)b * 1024 * 1024;
    const int r0 = (lane >> 4) * 4;
    #pragma unroll
    for (int n = 0; n < 4; ++n) {
        const int col = bcol + wc * 64 + n * 16 + fr;
        #pragma unroll
        for (int m = 0; m < 4; ++m) {
            const int row = brow + wr * 64 + m * 16 + r0;
            #pragma unroll
            for (int j = 0; j < 4; ++j)
                op[(size_t)(row + j) * 1024 + col] = 0.125f * acc[m][n][j];
        }
    }
}

extern "C" void kernel_launch(void* const* d_in, const int* in_sizes, int n_in,
                              void* d_out, int out_size, void* d_ws, size_t ws_size,
                              hipStream_t stream) {
    const float* rna  = (const float*)d_in[0];  // [8,1024,1280]
    const float* prot = (const float*)d_in[1];  // [8,1024,1344]
    const float* Wq   = (const float*)d_in[2];  // [512,1280]
    const float* bq   = (const float*)d_in[3];  // [512]
    const float* Wk   = (const float*)d_in[4];  // [512,1344]
    const float* bk   = (const float*)d_in[5];  // [512]
    const float* rb   = (const float*)d_in[6];  // [512] (flat idx == channel)

    __bf16* qws = (__bf16*)d_ws;                // [8192, 512] bf16 = 8 MB
    __bf16* kws = qws + (size_t)8192 * 512;     // [8192, 512] bf16 = 8 MB

    proj_all<<<dim3(512), dim3(512), 0, stream>>>(rna, prot, Wq, bq, Wk, bk, rb, qws, kws);
    attn_kernel<<<dim3(8, 8, 8), dim3(256), 0, stream>>>(qws, kws, (float*)d_out);
}

// Round 10
// 58.396 us; speedup vs baseline: 1.2797x; 1.2797x over previous
//
#include <hip/hip_runtime.h>
#include <hip/hip_bf16.h>

// CrossAttentionOutLayer: out[b,i,j] = (1/H) * sum_c Q'[b,i,c] * K[b,j,c]
//   Q' = SCALE*(rna@Wq.T + bq) + rel_bias   (c = h*DK+d == flat rel_bias idx)
//   K  = prot@Wk.T + bk
// B=8 N=1024 M=1024 DIM2=1280 KIN=1344 H=8 DK=64 HDK=512 SCALE=0.125
//
// R10: single-barrier K-step (T3-minimal). R9's 8-wave regressed (barrier
// cost scales with participants); R6/R8's 2-barrier step = m233's ~70%
// structural stall. Now: dbuf lets {ds_write tile t+1 -> buf[p^1]} and
// {ds_read tile t <- buf[p]} share ONE barrier interval; lgkmcnt(0) before
// the barrier both publishes writes and drains reads, so the next step may
// overwrite buf[p]. Loads for t+2 issued mid-step -> vmcnt(0) at next step
// top has a full step of cover (no drain stall, one reg set per operand).
// 4 waves (R8 geometry), setprio around MFMA cluster (T5: phase-split now).

typedef __bf16 bf16x8 __attribute__((ext_vector_type(8)));
typedef __bf16 bf16x4 __attribute__((ext_vector_type(4)));
typedef float f32x4 __attribute__((ext_vector_type(4)));

__device__ inline bf16x4 cvt4(const f32x4 a) {
    bf16x4 r;
    r[0] = (__bf16)a[0]; r[1] = (__bf16)a[1];
    r[2] = (__bf16)a[2]; r[3] = (__bf16)a[3];
    return r;
}

// unsinkable 16B global load; dst EARLY-CLOBBER (never aliases addr regs).
// NO implicit wait — caller must s_waitcnt vmcnt before reading dst.
__device__ inline void gload4(f32x4& dst, const float* p) {
    asm volatile("global_load_dwordx4 %0, %1, off"
                 : "=&v"(dst) : "v"(p) : "memory");
}

// ---------------------------------------------------------------------------
// Fused Q+K projection. Tile 128x128, BK=64, 4 waves (2x2) of 64x64.
// bf16 double-buffered LDS (64KB -> 2 blocks/CU). grid 512, XCD swizzle.
// ---------------------------------------------------------------------------
__global__ __launch_bounds__(256, 2)
void proj_all(const float* __restrict__ rna,  const float* __restrict__ prot,
              const float* __restrict__ Wq,   const float* __restrict__ bq,
              const float* __restrict__ Wk,   const float* __restrict__ bk,
              const float* __restrict__ rb,
              __bf16* __restrict__ qout, __bf16* __restrict__ kout)
{
    __shared__ __bf16 AS[2][128 * 64];   // 2 x 16 KB
    __shared__ __bf16 WS[2][128 * 64];   // 2 x 16 KB

    const int bid = blockIdx.x;
    const int wg  = (bid & 7) * 64 + (bid >> 3);   // bijective XCD swizzle (512%8==0)
    const bool isQ = wg < 256;
    const int lwg  = isQ ? wg : wg - 256;
    const int brow = (lwg >> 2) * 128;
    const int bcol = (lwg & 3) * 128;

    const float* A    = isQ ? rna : prot;
    const float* W    = isQ ? Wq  : Wk;
    const float* bias = isQ ? bq  : bk;
    __bf16*      out  = isQ ? qout : kout;
    const int    K    = isQ ? 1280 : 1344;
    const int    nt   = K >> 6;          // 20 (Q) or 21 (K) steps

    const int tid  = threadIdx.x;
    const int lane = tid & 63;
    const int wid  = tid >> 6;
    const int wr   = wid >> 1;
    const int wc   = wid & 1;
    const int fr   = lane & 15;
    const int q4   = lane >> 4;

    // staging: wave stages rows [wid*32, +32); instr i: row rloc+i*4, col fr*4
    const int rloc = wid * 32 + q4;
    const float* aGlob = A + (size_t)(brow + rloc) * K + fr * 4;
    const float* wGlob = W + (size_t)(bcol + rloc) * K + fr * 4;
    // LDS write addr: mask3(row)=((row&3)<<1)|((row>>2)&1); row&3=q4, (row>>2)&1=i&1
    const int lb = rloc * 128 + (((fr >> 1) ^ (q4 << 1)) << 4) + (lane & 1) * 8;
    // fragment-read swizzle (frag row&7 = fr&7)
    const int rmask = ((fr & 3) << 1) | ((fr >> 2) & 1);

    f32x4 acc[4][4] = {};
    f32x4 av[8], wv[8];                  // one prefetch set per operand

#define ISSUE_ALL(k0) do {                                                \
    _Pragma("unroll")                                                     \
    for (int i_ = 0; i_ < 8; ++i_)                                        \
        gload4(av[i_], aGlob + (size_t)(i_ * 4) * K + (k0));              \
    _Pragma("unroll")                                                     \
    for (int i_ = 0; i_ < 8; ++i_)                                        \
        gload4(wv[i_], wGlob + (size_t)(i_ * 4) * K + (k0));              \
    } while (0)

#define STAGE(p) do {                                                     \
    char* as_ = (char*)AS[p]; char* ws_ = (char*)WS[p];                   \
    _Pragma("unroll")                                                     \
    for (int i_ = 0; i_ < 8; ++i_) {                                      \
        *(bf16x4*)(as_ + ((lb ^ ((i_ & 1) << 4)) + i_ * 512)) = cvt4(av[i_]); \
        *(bf16x4*)(ws_ + ((lb ^ ((i_ & 1) << 4)) + i_ * 512)) = cvt4(wv[i_]); \
    } } while (0)

#define COMPUTE(p) do {                                                   \
    const char* as_ = (const char*)AS[p];                                 \
    const char* ws_ = (const char*)WS[p];                                 \
    __builtin_amdgcn_s_setprio(1);                                        \
    _Pragma("unroll")                                                     \
    for (int kk_ = 0; kk_ < 2; ++kk_) {                                   \
        bf16x8 af[4], bw[4];                                              \
        _Pragma("unroll")                                                 \
        for (int m_ = 0; m_ < 4; ++m_)                                    \
            af[m_] = *(const bf16x8*)(as_ + (wr * 64 + m_ * 16 + fr) * 128 \
                                          + (((kk_ * 4 + q4) ^ rmask) << 4)); \
        _Pragma("unroll")                                                 \
        for (int n_ = 0; n_ < 4; ++n_)                                    \
            bw[n_] = *(const bf16x8*)(ws_ + (wc * 64 + n_ * 16 + fr) * 128 \
                                          + (((kk_ * 4 + q4) ^ rmask) << 4)); \
        _Pragma("unroll")                                                 \
        for (int m_ = 0; m_ < 4; ++m_)                                    \
            _Pragma("unroll")                                             \
            for (int n_ = 0; n_ < 4; ++n_)                                \
                acc[m_][n_] = __builtin_amdgcn_mfma_f32_16x16x32_bf16(    \
                    af[m_], bw[n_], acc[m_][n_], 0, 0, 0);                \
    }                                                                     \
    __builtin_amdgcn_s_setprio(0);                                        \
    } while (0)

// STEP(t): entry invariant: buf[p] holds tile t (published); regs hold tile
// t+1 (issued one full step ago -> vmcnt(0) is covered). One barrier/step:
// write t+1 -> buf[p^1] and read t <- buf[p] share the interval (different
// buffers); lgkm(0)+s_barrier publishes writes AND licenses step t+1 to
// overwrite buf[p] (all reads drained). WAR regs (ds_write then asm load
// overwrite) safe: in-order issue reads operands before the load issues.
#define STEP(t, p) do {                                                   \
    asm volatile("s_waitcnt vmcnt(0)" ::: "memory");                      \
    __builtin_amdgcn_sched_barrier(0);   /* rule #18: no cvt hoist */     \
    if ((t) + 1 < nt) STAGE((p) ^ 1);                                     \
    if ((t) + 2 < nt) ISSUE_ALL(((t) + 2) * 64);                          \
    COMPUTE(p);                                                           \
    asm volatile("s_waitcnt lgkmcnt(0)" ::: "memory");                    \
    __builtin_amdgcn_s_barrier();                                         \
    __builtin_amdgcn_sched_barrier(0);                                    \
} while (0)

    // prologue: tile 0 -> buf[0] published; tile 1 loads in flight
    ISSUE_ALL(0);
    asm volatile("s_waitcnt vmcnt(0)" ::: "memory");
    __builtin_amdgcn_sched_barrier(0);
    STAGE(0);
    ISSUE_ALL(64);
    asm volatile("s_waitcnt lgkmcnt(0)" ::: "memory");
    __builtin_amdgcn_s_barrier();
    __builtin_amdgcn_sched_barrier(0);

    for (int t = 0; t + 1 < nt; t += 2) {    // pair-unroll: parity static
        STEP(t, 0);
        STEP(t + 1, 1);
    }
    if (nt & 1) STEP(nt - 1, 0);             // K-proj tail (nt=21)

#undef ISSUE_ALL
#undef STAGE
#undef COMPUTE
#undef STEP

    // C/D layout: col = lane&15, row = (lane>>4)*4 + j  [m89-verified]
    const int r0 = (lane >> 4) * 4;
    #pragma unroll
    for (int n = 0; n < 4; ++n) {
        const int c = bcol + wc * 64 + n * 16 + fr;
        const float bv = bias[c];
        const float rv = isQ ? rb[c] : 0.0f;
        #pragma unroll
        for (int m = 0; m < 4; ++m) {
            const int row = brow + wr * 64 + m * 16 + r0;
            #pragma unroll
            for (int j = 0; j < 4; ++j) {
                float v = acc[m][n][j] + bv;
                if (isQ) v = 0.125f * v + rv;
                out[(size_t)(row + j) * 512 + c] = (__bf16)v;
            }
        }
    }
}

// ---------------------------------------------------------------------------
// Batched GEMM: out[b,i,j] = 0.125 * sum_c Q[b,i,c]*K[b,j,c]
// 128x128 tile, BK=64, gload_lds staging, swizzled bf16 LDS. (unchanged;
// ~9.6 us ~= its HBM floor: 33.5 MB write + 16 MB read)
// ---------------------------------------------------------------------------
__global__ __launch_bounds__(256, 2)
void attn_kernel(const __bf16* __restrict__ Q,
                 const __bf16* __restrict__ Kb,
                 float* __restrict__ out)
{
    __shared__ __bf16 As[128 * 64];   // 16 KB, linear dest (swizzled content)
    __shared__ __bf16 Bs[128 * 64];

    const int tid  = threadIdx.x;
    const int lane = tid & 63;
    const int wid  = tid >> 6;
    const int wr   = wid >> 1;
    const int wc   = wid & 1;
    const int b    = blockIdx.z;
    const int brow = blockIdx.y * 128;
    const int bcol = blockIdx.x * 128;

    const __bf16* Qb = Q  + (size_t)b * 1024 * 512;
    const __bf16* Kp = Kb + (size_t)b * 1024 * 512;

    const int fr = lane & 15;
    const int q4 = lane >> 4;

    f32x4 acc[4][4] = {};

    const int lr3 = lane >> 3;
    const int m3  = ((lr3 & 3) << 1) | ((lr3 >> 2) & 1);
    const int scol = ((lane & 7) ^ m3) * 8;            // swizzled global bf16 col
    const int rmask = ((fr & 3) << 1) | ((fr >> 2) & 1);

    for (int k0 = 0; k0 < 512; k0 += 64) {
        __syncthreads();
        #pragma unroll
        for (int i = 0; i < 4; ++i) {
            const int rbase = wid * 32 + i * 8;
            const __bf16* sa = Qb + (size_t)(brow + rbase + lr3) * 512 + k0 + scol;
            const __bf16* sb = Kp + (size_t)(bcol + rbase + lr3) * 512 + k0 + scol;
            __builtin_amdgcn_global_load_lds(
                (const __attribute__((address_space(1))) void*)sa,
                (__attribute__((address_space(3))) void*)&As[rbase * 64], 16, 0, 0);
            __builtin_amdgcn_global_load_lds(
                (const __attribute__((address_space(1))) void*)sb,
                (__attribute__((address_space(3))) void*)&Bs[rbase * 64], 16, 0, 0);
        }
        __syncthreads();

        #pragma unroll
        for (int kk = 0; kk < 2; ++kk) {
            const int ci = kk * 4 + q4;
            bf16x8 af[4], bf_[4];
            #pragma unroll
            for (int m = 0; m < 4; ++m)
                af[m] = *(const bf16x8*)(&As[(wr * 64 + m * 16 + fr) * 64 + ((ci ^ rmask) << 3)]);
            #pragma unroll
            for (int n = 0; n < 4; ++n)
                bf_[n] = *(const bf16x8*)(&Bs[(wc * 64 + n * 16 + fr) * 64 + ((ci ^ rmask) << 3)]);
            #pragma unroll
            for (int m = 0; m < 4; ++m)
                #pragma unroll
                for (int n = 0; n < 4; ++n)
                    acc[m][n] = __builtin_amdgcn_mfma_f32_16x16x32_bf16(af[m], bf_[n], acc[m][n], 0, 0, 0);
        }
    }

    float* op = out + (size_t)b * 1024 * 1024;
    const int r0 = (lane >> 4) * 4;
    #pragma unroll
    for (int n = 0; n < 4; ++n) {
        const int col = bcol + wc * 64 + n * 16 + fr;
        #pragma unroll
        for (int m = 0; m < 4; ++m) {
            const int row = brow + wr * 64 + m * 16 + r0;
            #pragma unroll
            for (int j = 0; j < 4; ++j)
                op[(size_t)(row + j) * 1024 + col] = 0.125f * acc[m][n][j];
        }
    }
}

extern "C" void kernel_launch(void* const* d_in, const int* in_sizes, int n_in,
                              void* d_out, int out_size, void* d_ws, size_t ws_size,
                              hipStream_t stream) {
    const float* rna  = (const float*)d_in[0];  // [8,1024,1280]
    const float* prot = (const float*)d_in[1];  // [8,1024,1344]
    const float* Wq   = (const float*)d_in[2];  // [512,1280]
    const float* bq   = (const float*)d_in[3];  // [512]
    const float* Wk   = (const float*)d_in[4];  // [512,1344]
    const float* bk   = (const float*)d_in[5];  // [512]
    const float* rb   = (const float*)d_in[6];  // [512] (flat idx == channel)

    __bf16* qws = (__bf16*)d_ws;                // [8192, 512] bf16 = 8 MB
    __bf16* kws = qws + (size_t)8192 * 512;     // [8192, 512] bf16 = 8 MB

    proj_all<<<dim3(512), dim3(256), 0, stream>>>(rna, prot, Wq, bq, Wk, bk, rb, qws, kws);
    attn_kernel<<<dim3(8, 8, 8), dim3(256), 0, stream>>>(qws, kws, (float*)d_out);
}